// Round 8
// baseline (150.835 us; speedup 1.0000x reference)
//
#include <hip/hip_runtime.h>

typedef __bf16 bf16_t;
typedef bf16_t bf16x8 __attribute__((ext_vector_type(8)));
typedef float f32x4 __attribute__((ext_vector_type(4)));
typedef float f32x16 __attribute__((ext_vector_type(16)));
typedef unsigned short u16x4 __attribute__((ext_vector_type(4)));
typedef unsigned int u32x4v __attribute__((ext_vector_type(4)));
typedef unsigned int u32;

#define DEV static __device__ __forceinline__

// ---------- helpers ----------

DEV unsigned short f2bf(float f) {
  unsigned int u = __builtin_bit_cast(unsigned int, f);
  u = (u + 0x7fffu + ((u >> 16) & 1u)) >> 16;  // RNE
  return (unsigned short)u;
}

DEV float fexp2(float x) {  // 2^x via v_exp_f32
  float r;
  asm("v_exp_f32 %0, %1" : "=v"(r) : "v"(x));
  return r;
}

DEV u32 cvtpk(float lo, float hi_) {  // packed bf16 pair (RNE)
  u32 r;
  asm("v_cvt_pk_bf16_f32 %0, %1, %2" : "=v"(r) : "v"(lo), "v"(hi_));
  return r;
}

DEV void plswap(u32& a, u32& b) {  // swap a.hi32lanes <-> b.lo32lanes
  asm("v_permlane32_swap_b32 %0, %1" : "+v"(a), "+v"(b));
}

DEV void async_ld16(const unsigned short* gsrc, unsigned short* lbase, int lane) {
#if __has_builtin(__builtin_amdgcn_global_load_lds)
  __builtin_amdgcn_global_load_lds(
      (const __attribute__((address_space(1))) unsigned int*)(const void*)gsrc,
      (__attribute__((address_space(3))) unsigned int*)(void*)lbase, 16, 0, 0);
#else
  *reinterpret_cast<u32x4v*>(reinterpret_cast<char*>(lbase) + lane * 16) =
      *reinterpret_cast<const u32x4v*>(gsrc);
#endif
}

// ---------- fp32 -> bf16 convert (weights only; q/k/v converted in-GEMM) ----------

__global__ __launch_bounds__(256) void cvt_w(const float* __restrict__ a,
                                             const float* __restrict__ b,
                                             const float* __restrict__ c,
                                             const float* __restrict__ d, unsigned short* da,
                                             unsigned short* db_, unsigned short* dc,
                                             unsigned short* dd) {
  const int i = blockIdx.x * 256 + threadIdx.x;
  const float* src = blockIdx.z == 0 ? a : blockIdx.z == 1 ? b : blockIdx.z == 2 ? c : d;
  unsigned short* dst = blockIdx.z == 0 ? da : blockIdx.z == 1 ? db_ : blockIdx.z == 2 ? dc : dd;
  const float4* s = reinterpret_cast<const float4*>(src) + (size_t)i * 2;
  float4 x = s[0], y = s[1];
  u16x4 lo = {f2bf(x.x), f2bf(x.y), f2bf(x.z), f2bf(x.w)};
  u16x4 hi = {f2bf(y.x), f2bf(y.y), f2bf(y.z), f2bf(y.w)};
  u16x4* dptr = reinterpret_cast<u16x4*>(dst) + (size_t)i * 2;
  dptr[0] = lo;
  dptr[1] = hi;
}

// ---------- 128x128-tile GEMM cores, BK=64, 2-phase dbuf (R5-proven schedule) ----------

DEV void stage_b128(const unsigned short* __restrict__ G, int row0, int k0,
                    unsigned short* lbuf, int lane, int wv) {
#pragma unroll
  for (int r = 0; r < 4; ++r) {
    const int rowB = (r * 4 + wv) * 8 + (lane >> 3);
    const int chunk = (lane & 7) ^ (rowB & 7);
    async_ld16(G + (size_t)(row0 + rowB) * 1024 + k0 + chunk * 8, lbuf + (r * 4 + wv) * 512,
               lane);
  }
}

// A-operand reg-staging from fp32: 8 float4 loads/lane (issue-early), then
// cvt_pk + 4 ds_write_b128 into the XOR-swizzled layout (write-late).
DEV void stage_a_ld(const float* __restrict__ X, int row0, int k0, int lane, int wv,
                    float4 rg[8]) {
  const int r0 = lane >> 3, chunk = lane & 7;
#pragma unroll
  for (int c2 = 0; c2 < 4; ++c2) {
    const float* g = X + (size_t)(row0 + wv * 32 + r0 + 8 * c2) * 1024 + k0 + chunk * 8;
    rg[c2 * 2] = *reinterpret_cast<const float4*>(g);
    rg[c2 * 2 + 1] = *reinterpret_cast<const float4*>(g + 4);
  }
}

DEV void stage_a_wr(unsigned short* lbuf, int lane, int wv, const float4 rg[8]) {
  const int r0 = lane >> 3, chunk = lane & 7;
#pragma unroll
  for (int c2 = 0; c2 < 4; ++c2) {
    const int row = wv * 32 + r0 + 8 * c2;
    const int p = chunk ^ (row & 7);
    u32x4v w;
    w[0] = cvtpk(rg[c2 * 2].x, rg[c2 * 2].y);
    w[1] = cvtpk(rg[c2 * 2].z, rg[c2 * 2].w);
    w[2] = cvtpk(rg[c2 * 2 + 1].x, rg[c2 * 2 + 1].y);
    w[3] = cvtpk(rg[c2 * 2 + 1].z, rg[c2 * 2 + 1].w);
    *reinterpret_cast<u32x4v*>(lbuf + row * 64 + p * 8) = w;
  }
}

DEV void mfma_step(const unsigned short* lA, const unsigned short* lB, int lane, int wm, int wn,
                   f32x4 acc[4][4]) {
#pragma unroll
  for (int kk = 0; kk < 2; ++kk) {
    bf16x8 af[4], bfr[4];
#pragma unroll
    for (int f = 0; f < 4; ++f) {
      const int rowA = wm * 64 + f * 16 + (lane & 15);
      const int cA = (kk * 4 + (lane >> 4)) ^ (rowA & 7);
      af[f] = *reinterpret_cast<const bf16x8*>(lA + rowA * 64 + cA * 8);
      const int rowB = wn * 64 + f * 16 + (lane & 15);
      const int cB = (kk * 4 + (lane >> 4)) ^ (rowB & 7);
      bfr[f] = *reinterpret_cast<const bf16x8*>(lB + rowB * 64 + cB * 8);
    }
#pragma unroll
    for (int i = 0; i < 4; ++i)
#pragma unroll
      for (int j = 0; j < 4; ++j)
        acc[i][j] = __builtin_amdgcn_mfma_f32_16x16x32_bf16(af[i], bfr[j], acc[i][j], 0, 0, 0);
  }
}

// core with fp32 A (QKV projections)
DEV void gemm_core_f32a(const float* __restrict__ X, const unsigned short* __restrict__ W,
                        unsigned short* lA0, unsigned short* lA1, unsigned short* lB0,
                        unsigned short* lB1, int bm0, int bn0, int lane, int wv, int wm, int wn,
                        f32x4 acc[4][4]) {
  float4 rg[8];
  stage_a_ld(X, bm0, 0, lane, wv, rg);
  stage_b128(W, bn0, 0, lB0, lane, wv);
  stage_a_wr(lA0, lane, wv, rg);
  __syncthreads();
  for (int kt = 0; kt < 16; ++kt) {
    unsigned short* lA = (kt & 1) ? lA1 : lA0;
    unsigned short* lB = (kt & 1) ? lB1 : lB0;
    unsigned short* nA = (kt & 1) ? lA0 : lA1;
    unsigned short* nB = (kt & 1) ? lB0 : lB1;
    if (kt < 15) {  // issue next-tile loads EARLY (A->regs, B->LDS async)
      stage_a_ld(X, bm0, (kt + 1) * 64, lane, wv, rg);
      stage_b128(W, bn0, (kt + 1) * 64, nB, lane, wv);
    }
    mfma_step(lA, lB, lane, wm, wn, acc);  // HBM latency hides under this
    if (kt < 15) stage_a_wr(nA, lane, wv, rg);  // write-late after compute
    __syncthreads();
  }
}

// core with bf16 A (output projection)
DEV void gemm_core_bf16a(const unsigned short* __restrict__ X,
                         const unsigned short* __restrict__ W, unsigned short* lA0,
                         unsigned short* lA1, unsigned short* lB0, unsigned short* lB1, int bm0,
                         int bn0, int lane, int wv, int wm, int wn, f32x4 acc[4][4]) {
  stage_b128(X, bm0, 0, lA0, lane, wv);
  stage_b128(W, bn0, 0, lB0, lane, wv);
  __syncthreads();
  for (int kt = 0; kt < 16; ++kt) {
    unsigned short* lA = (kt & 1) ? lA1 : lA0;
    unsigned short* lB = (kt & 1) ? lB1 : lB0;
    unsigned short* nA = (kt & 1) ? lA0 : lA1;
    unsigned short* nB = (kt & 1) ? lB0 : lB1;
    if (kt < 15) {
      stage_b128(X, bm0, (kt + 1) * 64, nA, lane, wv);
      stage_b128(W, bn0, (kt + 1) * 64, nB, lane, wv);
    }
    mfma_step(lA, lB, lane, wm, wn, acc);
    __syncthreads();
  }
}

// ---------- QKV projection; Q,K -> [B,H,S,dk]; V -> TRANSPOSED [B,H,dk,S] ----------
// A read directly from fp32 inputs; K-head-norm maxes folded into epilogue (z==1).

__global__ __launch_bounds__(256) void gemm_qkv_kernel(
    const float* __restrict__ Xq, const float* __restrict__ Xk, const float* __restrict__ Xv,
    const unsigned short* __restrict__ Wq, const unsigned short* __restrict__ Wk,
    const unsigned short* __restrict__ Wv, const float* __restrict__ bq,
    const float* __restrict__ bk, const float* __restrict__ bv, unsigned short* __restrict__ Qp,
    unsigned short* __restrict__ Kp, unsigned short* __restrict__ Vp,
    unsigned* __restrict__ nb2) {
  __shared__ unsigned short lA[2][8192];
  __shared__ unsigned short lB[2][8192];
  // bijective XCD swizzle (nwg=768, %8==0): contiguous logical tiles per XCD
  const int flat = blockIdx.x + 32 * blockIdx.y + 256 * blockIdx.z;
  const int swz = (flat & 7) * 96 + (flat >> 3);
  const int bx = swz & 31;
  const int by = (swz >> 5) & 7;
  const int bz = swz >> 8;
  const float* X;
  const unsigned short* W;
  const float* bias;
  unsigned short* dst;
  if (bz == 0) { X = Xq; W = Wq; bias = bq; dst = Qp; }
  else if (bz == 1) { X = Xk; W = Wk; bias = bk; dst = Kp; }
  else { X = Xv; W = Wv; bias = bv; dst = Vp; }
  const bool zV = (bz == 2);
  const bool zK = (bz == 1) && (nb2 != nullptr);
  const int lane = threadIdx.x & 63, wv = threadIdx.x >> 6;
  const int wm = wv >> 1, wn = wv & 1;
  const int bm0 = bx * 128, bn0 = by * 128;
  f32x4 acc[4][4] = {};
  gemm_core_f32a(X, W, lA[0], lA[1], lB[0], lB[1], bm0, bn0, lane, wv, wm, wn, acc);
  float rowmax = 0.0f;
#pragma unroll
  for (int i = 0; i < 4; ++i) {
    const int mbase = bm0 + wm * 64 + i * 16 + ((lane >> 4) << 2);
#pragma unroll
    for (int r = 0; r < 4; ++r) {
      const int m = mbase + r;
      const int b = m >> 11, s = m & 2047;
      float ssp = 0.0f;
#pragma unroll
      for (int j = 0; j < 4; ++j) {
        const int n = bn0 + wn * 64 + j * 16 + (lane & 15);
        const float val = acc[i][j][r] + bias[n];
        const unsigned short v16 = f2bf(val);
        const int h = n >> 6, d = n & 63;
        if (zV)
          dst[((size_t)(b * 16 + h) * 64 + d) * 2048 + s] = v16;
        else
          dst[((size_t)(b * 16 + h) * 2048 + s) * 64 + d] = v16;
        ssp = __builtin_fmaf(val, val, ssp);
      }
      if (zK) {  // this wave's cols span exactly one head: reduce over lane&15
        ssp += __shfl_xor(ssp, 1);
        ssp += __shfl_xor(ssp, 2);
        ssp += __shfl_xor(ssp, 4);
        ssp += __shfl_xor(ssp, 8);
        rowmax = fmaxf(rowmax, ssp);
      }
    }
  }
  if (zK) {
    rowmax = fmaxf(rowmax, __shfl_xor(rowmax, 16));
    rowmax = fmaxf(rowmax, __shfl_xor(rowmax, 32));
    if (lane == 0) {
      const int head = (bm0 >> 11) * 16 + by * 2 + wn;
      atomicMax(nb2 + head, __float_as_uint(rowmax));
    }
  }
}

// ---------- output projection ----------

__global__ __launch_bounds__(256) void gemm_out_kernel(const unsigned short* __restrict__ X,
                                                       const unsigned short* __restrict__ W,
                                                       const float* __restrict__ bias,
                                                       float* __restrict__ out) {
  __shared__ unsigned short lA[2][8192];
  __shared__ unsigned short lB[2][8192];
  const int flat = blockIdx.x + 32 * blockIdx.y;  // nwg=256, %8==0
  const int swz = (flat & 7) * 32 + (flat >> 3);
  const int bx = swz & 31, by = swz >> 5;
  const int lane = threadIdx.x & 63, wv = threadIdx.x >> 6;
  const int wm = wv >> 1, wn = wv & 1;
  const int bm0 = bx * 128, bn0 = by * 128;
  f32x4 acc[4][4] = {};
  gemm_core_bf16a(X, W, lA[0], lA[1], lB[0], lB[1], bm0, bn0, lane, wv, wm, wn, acc);
#pragma unroll
  for (int i = 0; i < 4; ++i) {
    const int mbase = bm0 + wm * 64 + i * 16 + ((lane >> 4) << 2);
#pragma unroll
    for (int j = 0; j < 4; ++j) {
      const int n = bn0 + wn * 64 + j * 16 + (lane & 15);
      const float bia = bias[n];
#pragma unroll
      for (int r = 0; r < 4; ++r) out[(size_t)(mbase + r) * 1024 + n] = acc[i][j][r] + bia;
    }
  }
}

// ---------- K-norm fallback (compact-ws only): nb2[bh] = max_s ||k_s||^2 ----------

__global__ __launch_bounds__(256) void knorm_kernel(const unsigned short* __restrict__ Kp,
                                                    unsigned* __restrict__ nb2) {
  const int bh = blockIdx.y;
  const int s = blockIdx.x * 256 + threadIdx.x;
  const u32x4v* row = reinterpret_cast<const u32x4v*>(Kp + ((size_t)bh * 2048 + s) * 64);
  float ss = 0.0f;
#pragma unroll
  for (int c = 0; c < 8; ++c) {
    u32x4v u = row[c];
#pragma unroll
    for (int e = 0; e < 4; ++e) {
      const float lo = __builtin_bit_cast(float, u[e] << 16);
      const float hi = __builtin_bit_cast(float, u[e] & 0xFFFF0000u);
      ss = __builtin_fmaf(lo, lo, ss);
      ss = __builtin_fmaf(hi, hi, ss);
    }
  }
#pragma unroll
  for (int off = 1; off <= 32; off <<= 1) ss = fmaxf(ss, __shfl_xor(ss, off));
  if ((threadIdx.x & 63) == 0) atomicMax(nb2 + bh, __float_as_uint(ss));
}

// ---------- prepass: per (bh, qt64): m_floor (tile-0 row-max min, j-domain) + blt ----------

__global__ __launch_bounds__(128) void attn_prepass(const unsigned short* __restrict__ Qp,
                                                    const unsigned short* __restrict__ Kp,
                                                    const unsigned* __restrict__ nb2,
                                                    float* __restrict__ mfA,
                                                    float* __restrict__ bltA) {
  __shared__ float sred[4];
  const int lane = threadIdx.x & 63, wv = threadIdx.x >> 6;
  const int lq = lane & 31, hi = lane >> 5;
  const int qt = blockIdx.x, bh = blockIdx.y, h = bh & 15;
  const float L2E = 1.4426950408889634f;
  const float slope2 = ldexpf(L2E, h - 8);
  const float SC2 = 0.125f * L2E;
  const size_t headoff = (size_t)bh * 2048 * 64;
  const unsigned short* Qh = Qp + headoff;
  const unsigned short* Kh = Kp + headoff;
  const int q_glob = qt * 64 + wv * 32 + lq;

  bf16x8 qf[4];
#pragma unroll
  for (int tt = 0; tt < 4; ++tt)
    qf[tt] = *reinterpret_cast<const bf16x8*>(Qh + (size_t)q_glob * 64 + tt * 16 + hi * 8);

  float qq = 0.0f;
#pragma unroll
  for (int tt = 0; tt < 4; ++tt)
#pragma unroll
    for (int e = 0; e < 8; ++e) {
      const float x = (float)qf[tt][e];
      qq = __builtin_fmaf(x, x, qq);
    }
  qq += __shfl_xor(qq, 32);
#pragma unroll
  for (int off = 1; off <= 16; off <<= 1) qq = fmaxf(qq, __shfl_xor(qq, off));

  f32x16 s0 = {}, s1 = {};
#pragma unroll
  for (int tt = 0; tt < 4; ++tt) {
    bf16x8 k0 = *reinterpret_cast<const bf16x8*>(Kh + (size_t)lq * 64 + tt * 16 + hi * 8);
    s0 = __builtin_amdgcn_mfma_f32_32x32x16_bf16(k0, qf[tt], s0, 0, 0, 0);
    bf16x8 k1 = *reinterpret_cast<const bf16x8*>(Kh + (size_t)(32 + lq) * 64 + tt * 16 + hi * 8);
    s1 = __builtin_amdgcn_mfma_f32_32x32x16_bf16(k1, qf[tt], s1, 0, 0, 0);
  }
  float zmax = -3.0e38f;
#pragma unroll
  for (int r = 0; r < 16; ++r) {
    const float cb = -slope2 * (float)(4 * hi + (r & 3) + 8 * (r >> 2));
    const float x0 = __builtin_fmaf(s0[r], SC2, cb);
    const float x1 = __builtin_fmaf(s1[r], SC2, cb - slope2 * 32.0f);
    zmax = fmaxf(zmax, fmaxf(x0, x1));
  }
  zmax = fmaxf(zmax, __shfl_xor(zmax, 32));
  float zmin = zmax;
#pragma unroll
  for (int off = 1; off <= 16; off <<= 1) zmin = fminf(zmin, __shfl_xor(zmin, off));
  if (lane == 0) {
    sred[wv] = zmin;
    sred[2 + wv] = qq;
  }
  __syncthreads();
  if (threadIdx.x == 0) {
    const float mf = fminf(sred[0], sred[1]);
    const float qn = sqrtf(fmaxf(sred[2], sred[3]));
    const float nk = sqrtf(__uint_as_float(nb2[bh]));
    mfA[bh * 32 + qt] = mf;
    bltA[bh * 32 + qt] = qn * nk * SC2;
  }
}

// ---------- flash attention KV-split: partial (m,l,O) per (bh,qt,split) ----------

DEV void stage_tile64(const unsigned short* __restrict__ Gbase, size_t stride, int colbase,
                      unsigned short* lbuf, int lane, int wv) {
#pragma unroll
  for (int i = 0; i < 4; ++i) {
    const int r = i * 16 + wv * 8 + (lane >> 3);
    const int chunk = (lane & 7) ^ (r & 7);
    async_ld16(Gbase + (size_t)r * stride + colbase + chunk * 8, lbuf + (i * 16 + wv * 8) * 64,
               lane);
  }
}

__global__ __launch_bounds__(128) void attn_split_kernel(
    const unsigned short* __restrict__ Qp, const unsigned short* __restrict__ Kp,
    const unsigned short* __restrict__ VTp, const float* __restrict__ mfA,
    const float* __restrict__ bltA, float* __restrict__ ML, float* __restrict__ Opart, int Ct,
    int nsplit) {
  __shared__ unsigned short Kb[2][64 * 64];
  __shared__ unsigned short Vb[2][64 * 64];
  const int lane = threadIdx.x & 63, wv = threadIdx.x >> 6;
  const int lq = lane & 31, hi = lane >> 5;
  const int qt = blockIdx.x, sp = blockIdx.y, bh = blockIdx.z;
  const int h = bh & 15;
  const int idx = bh * 32 + qt;
  const float L2E = 1.4426950408889634f;
  const float slope2 = ldexpf(L2E, h - 8);
  const float SC2 = 0.125f * L2E;
  const float m_floor = mfA[idx], blt = bltA[idx];
  const float tf = (blt - m_floor + 34.0f) / (slope2 * 64.0f);
  const int T_act = min(32, (int)tf + 1);
  const int t0 = sp * Ct;
  const int nt = min(Ct, T_act - t0);
  float* mlb = ML + ((size_t)idx * nsplit + sp) * 128;
  if (nt <= 0) {  // inactive split: sentinel only
    mlb[threadIdx.x] = threadIdx.x < 64 ? -3.0e38f : 0.0f;
    return;
  }
  float* ob = Opart + ((size_t)idx * nsplit + sp) * 4096;
  const size_t headoff = (size_t)bh * 2048 * 64;
  const unsigned short* Qh = Qp + headoff;
  const unsigned short* Kh = Kp + headoff;
  const unsigned short* VTh = VTp + headoff;
  const int q_glob = qt * 64 + wv * 32 + lq;

  float cb0[16], cb1[16];
#pragma unroll
  for (int r = 0; r < 16; ++r) {
    cb0[r] = -slope2 * (float)(4 * hi + (r & 3) + 8 * (r >> 2));
    cb1[r] = cb0[r] - slope2 * 32.0f;
  }

  bf16x8 qf[4];
#pragma unroll
  for (int tt = 0; tt < 4; ++tt)
    qf[tt] = *reinterpret_cast<const bf16x8*>(Qh + (size_t)q_glob * 64 + tt * 16 + hi * 8);

  stage_tile64(Kh + (size_t)(t0 * 64) * 64, 64, 0, Kb[0], lane, wv);
  stage_tile64(VTh, 2048, t0 * 64, Vb[0], lane, wv);
  __syncthreads();

  f32x16 acc0 = {}, acc1 = {};
  float m_run = m_floor, l_run = 0.0f;

  for (int ti = 0; ti < nt; ++ti) {
    const int kv0 = (t0 + ti) * 64;
    const float s2k = slope2 * (float)kv0;
    const unsigned short* Kc = Kb[ti & 1];
    const unsigned short* Vc = Vb[ti & 1];
    if (ti + 1 < nt) {
      stage_tile64(Kh + (size_t)(kv0 + 64) * 64, 64, 0, Kb[(ti + 1) & 1], lane, wv);
      stage_tile64(VTh, 2048, kv0 + 64, Vb[(ti + 1) & 1], lane, wv);
    }
    f32x16 s0 = {}, s1 = {};
    __builtin_amdgcn_s_setprio(1);
#pragma unroll
    for (int tt = 0; tt < 4; ++tt) {
      {
        const int row = lq;
        const int ch = (tt * 2 + hi) ^ (row & 7);
        bf16x8 kf = *reinterpret_cast<const bf16x8*>(Kc + row * 64 + ch * 8);
        s0 = __builtin_amdgcn_mfma_f32_32x32x16_bf16(kf, qf[tt], s0, 0, 0, 0);
      }
      {
        const int row = 32 + lq;
        const int ch = (tt * 2 + hi) ^ (row & 7);
        bf16x8 kf = *reinterpret_cast<const bf16x8*>(Kc + row * 64 + ch * 8);
        s1 = __builtin_amdgcn_mfma_f32_32x32x16_bf16(kf, qf[tt], s1, 0, 0, 0);
      }
    }
    __builtin_amdgcn_s_setprio(0);
    float zmax = -3.0e38f;
#pragma unroll
    for (int r = 0; r < 16; ++r) {
      s0[r] = __builtin_fmaf(s0[r], SC2, cb0[r]);
      s1[r] = __builtin_fmaf(s1[r], SC2, cb1[r]);
      zmax = fmaxf(zmax, fmaxf(s0[r], s1[r]));
    }
    zmax = fmaxf(zmax, __shfl_xor(zmax, 32));
    const float tmax_true = zmax - s2k;
    if (__any(tmax_true > m_run + 8.0f)) {  // defer-max
      const float m_new = fmaxf(m_run, tmax_true);
      const float alpha = fexp2(m_run - m_new);
      m_run = m_new;
      l_run *= alpha;
      acc0 *= alpha;
      acc1 *= alpha;
    }
    const float mm = m_run + s2k;
    float ps0 = 0.0f, ps1 = 0.0f;
#pragma unroll
    for (int r = 0; r < 16; ++r) {
      const float p0 = fexp2(s0[r] - mm);
      const float p1 = fexp2(s1[r] - mm);
      s0[r] = p0;
      s1[r] = p1;
      ps0 += p0;
      ps1 += p1;
    }
    float psum = ps0 + ps1;
    psum += __shfl_xor(psum, 32);
    l_run += psum;
    bf16x8 pf[4];
#pragma unroll
    for (int half = 0; half < 2; ++half) {
      u32 w0 = cvtpk(s0[half * 8 + 0], s0[half * 8 + 1]);
      u32 w2 = cvtpk(s0[half * 8 + 4], s0[half * 8 + 5]);
      plswap(w0, w2);
      u32 w1 = cvtpk(s0[half * 8 + 2], s0[half * 8 + 3]);
      u32 w3 = cvtpk(s0[half * 8 + 6], s0[half * 8 + 7]);
      plswap(w1, w3);
      u32x4v ww = {w0, w1, w2, w3};
      pf[half] = __builtin_bit_cast(bf16x8, ww);
    }
#pragma unroll
    for (int half = 0; half < 2; ++half) {
      u32 w0 = cvtpk(s1[half * 8 + 0], s1[half * 8 + 1]);
      u32 w2 = cvtpk(s1[half * 8 + 4], s1[half * 8 + 5]);
      plswap(w0, w2);
      u32 w1 = cvtpk(s1[half * 8 + 2], s1[half * 8 + 3]);
      u32 w3 = cvtpk(s1[half * 8 + 6], s1[half * 8 + 7]);
      plswap(w1, w3);
      u32x4v ww = {w0, w1, w2, w3};
      pf[2 + half] = __builtin_bit_cast(bf16x8, ww);
    }
    __builtin_amdgcn_s_setprio(1);
#pragma unroll
    for (int tt = 0; tt < 4; ++tt) {
      {
        const int row = lq;
        const int ch = (tt * 2 + hi) ^ (row & 7);
        bf16x8 vf = *reinterpret_cast<const bf16x8*>(Vc + row * 64 + ch * 8);
        acc0 = __builtin_amdgcn_mfma_f32_32x32x16_bf16(vf, pf[tt], acc0, 0, 0, 0);
      }
      {
        const int row = 32 + lq;
        const int ch = (tt * 2 + hi) ^ (row & 7);
        bf16x8 vf = *reinterpret_cast<const bf16x8*>(Vc + row * 64 + ch * 8);
        acc1 = __builtin_amdgcn_mfma_f32_32x32x16_bf16(vf, pf[tt], acc1, 0, 0, 0);
      }
    }
    __builtin_amdgcn_s_setprio(0);
    __syncthreads();
  }
  const int qloc = wv * 32 + lq;
  if (hi == 0) {
    mlb[qloc] = m_run;
    mlb[64 + qloc] = l_run;
  }
#pragma unroll
  for (int g = 0; g < 4; ++g) {
    f32x4 w0, w1;
#pragma unroll
    for (int e = 0; e < 4; ++e) {
      w0[e] = acc0[g * 4 + e];
      w1[e] = acc1[g * 4 + e];
    }
    *reinterpret_cast<f32x4*>(ob + qloc * 64 + g * 8 + 4 * hi) = w0;
    *reinterpret_cast<f32x4*>(ob + qloc * 64 + 32 + g * 8 + 4 * hi) = w1;
  }
}

// ---------- combine partials -> Obf bf16 [B,S,H*64] ----------

__global__ __launch_bounds__(256) void attn_combine(const float* __restrict__ ML,
                                                    const float* __restrict__ Opart,
                                                    unsigned short* __restrict__ Ob, int nsplit) {
  const int idx = blockIdx.x;  // bh*32 + qt
  const int bh = idx >> 5, qt = idx & 31;
  const int h = bh & 15, b = bh >> 4;
  const int q = threadIdx.x >> 2, d0 = (threadIdx.x & 3) * 16;
  const float* mlb = ML + (size_t)idx * nsplit * 128;
  const float* ob = Opart + (size_t)idx * nsplit * 4096;
  float m_g = -3.0e38f;
  for (int s = 0; s < nsplit; ++s) m_g = fmaxf(m_g, mlb[s * 128 + q]);
  float l = 0.0f;
  f32x4 acc[4] = {};
  for (int s = 0; s < nsplit; ++s) {
    const float ms = mlb[s * 128 + q], ls = mlb[s * 128 + 64 + q];
    const float w = fexp2(ms - m_g);
    const float wl = w * ls;
    if (wl > 0.0f) {
      l += wl;
      const f32x4* src = reinterpret_cast<const f32x4*>(ob + (size_t)s * 4096 + q * 64 + d0);
#pragma unroll
      for (int j = 0; j < 4; ++j) {
        f32x4 v = src[j];
#pragma unroll
        for (int e = 0; e < 4; ++e) acc[j][e] = __builtin_fmaf(w, v[e], acc[j][e]);
      }
    }
  }
  const float invl = 1.0f / l;
  unsigned short* orow = Ob + ((size_t)(b * 2048 + qt * 64 + q)) * 1024 + h * 64 + d0;
#pragma unroll
  for (int j = 0; j < 4; ++j) {
    u16x4 pk;
#pragma unroll
    for (int e = 0; e < 4; ++e) pk[e] = f2bf(acc[j][e] * invl);
    *reinterpret_cast<u16x4*>(orow + j * 4) = pk;
  }
}

// ---------- launcher ----------

extern "C" void kernel_launch(void* const* d_in, const int* in_sizes, int n_in, void* d_out,
                              int out_size, void* d_ws, size_t ws_size, hipStream_t stream) {
  const float* q = (const float*)d_in[0];
  const float* k = (const float*)d_in[1];
  const float* v = (const float*)d_in[2];
  const float* Wq = (const float*)d_in[3];
  const float* bq = (const float*)d_in[4];
  const float* Wk = (const float*)d_in[5];
  const float* bk = (const float*)d_in[6];
  const float* Wv = (const float*)d_in[7];
  const float* bv = (const float*)d_in[8];
  const float* Wo = (const float*)d_in[9];
  const float* bo = (const float*)d_in[10];

  char* ws = (char*)d_ws;
  const size_t MB = 1024 * 1024;
  unsigned short* Wqb = (unsigned short*)(ws + 24 * MB);  // dead after gemm_qkv
  unsigned short* Wkb = (unsigned short*)(ws + 26 * MB);  // dead after gemm_qkv
  unsigned short* Wvb = (unsigned short*)(ws + 28 * MB);  // dead after gemm_qkv
  unsigned short* Wob = (unsigned short*)(ws + 30 * MB);  // LIVE until gemm_out
  unsigned short* Qp = (unsigned short*)(ws + 32 * MB);
  unsigned short* Kp = (unsigned short*)(ws + 40 * MB);
  unsigned short* VTp = (unsigned short*)(ws + 48 * MB);
  unsigned short* Obf = (unsigned short*)(ws + 0 * MB);  // 8MB

  int nsplit;
  float *mfA, *bltA, *ML, *Opart;
  unsigned* nb2;
  bool fold_knorm;
  if (ws_size >= (size_t)121 * MB) nsplit = 4;
  else if (ws_size >= (size_t)89 * MB) nsplit = 2;
  else nsplit = 1;
  if (ws_size >= (size_t)73 * MB) {
    fold_knorm = true;
    nb2 = (unsigned*)(ws + 56 * MB);  // beyond all gemm I/O: safe for in-gemm atomics
    mfA = (float*)(ws + 24 * MB + 4096);  // note: written AFTER gemm (prepass) - Wqb dead then
    bltA = (float*)(ws + 24 * MB + 8192);
    ML = (float*)(ws + 26 * MB + 65536);  // after nb2-fallback region; Wkb dead post-gemm
    Opart = (float*)(ws + 56 * MB + 4096);
  } else {
    fold_knorm = false;
    nsplit = 1;
    nb2 = (unsigned*)(ws + 26 * MB);  // Wkb region, written only AFTER gemm (knorm kernel)
    mfA = (float*)(ws + 26 * MB + 4096);
    bltA = (float*)(ws + 26 * MB + 8192);
    ML = (float*)(ws + 26 * MB + 65536);
    Opart = (float*)(ws + 8 * MB);
  }
  const int Ct = 32 / nsplit;

  cvt_w<<<dim3(512, 1, 4), 256, 0, stream>>>(Wq, Wk, Wv, Wo, Wqb, Wkb, Wvb, Wob);
  hipMemsetAsync(nb2, 0, 64 * sizeof(unsigned), stream);
  gemm_qkv_kernel<<<dim3(32, 8, 3), 256, 0, stream>>>(q, k, v, Wqb, Wkb, Wvb, bq, bk, bv, Qp, Kp,
                                                      VTp, fold_knorm ? nb2 : nullptr);
  if (!fold_knorm) knorm_kernel<<<dim3(8, 32), 256, 0, stream>>>(Kp, nb2);
  attn_prepass<<<dim3(32, 32), 128, 0, stream>>>(Qp, Kp, nb2, mfA, bltA);
  attn_split_kernel<<<dim3(32, nsplit, 32), 128, 0, stream>>>(Qp, Kp, VTp, mfA, bltA, ML, Opart,
                                                              Ct, nsplit);
  attn_combine<<<1024, 256, 0, stream>>>(ML, Opart, Obf, nsplit);
  gemm_out_kernel<<<dim3(32, 8), 256, 0, stream>>>(Obf, Wob, bo, (float*)d_out);
}

// Round 9
// 124.615 us; speedup vs baseline: 1.2104x; 1.2104x over previous
//
#include <hip/hip_runtime.h>

typedef __bf16 bf16_t;
typedef bf16_t bf16x8 __attribute__((ext_vector_type(8)));
typedef float f32x4 __attribute__((ext_vector_type(4)));
typedef float f32x16 __attribute__((ext_vector_type(16)));
typedef unsigned short u16x4 __attribute__((ext_vector_type(4)));
typedef unsigned int u32x4v __attribute__((ext_vector_type(4)));
typedef unsigned int u32;

#define DEV static __device__ __forceinline__

// ---------- helpers ----------

DEV unsigned short f2bf(float f) {
  unsigned int u = __builtin_bit_cast(unsigned int, f);
  u = (u + 0x7fffu + ((u >> 16) & 1u)) >> 16;  // RNE
  return (unsigned short)u;
}

DEV float fexp2(float x) {  // 2^x via v_exp_f32
  float r;
  asm("v_exp_f32 %0, %1" : "=v"(r) : "v"(x));
  return r;
}

DEV u32 cvtpk(float lo, float hi_) {  // packed bf16 pair (RNE)
  u32 r;
  asm("v_cvt_pk_bf16_f32 %0, %1, %2" : "=v"(r) : "v"(lo), "v"(hi_));
  return r;
}

DEV void plswap(u32& a, u32& b) {  // swap a.hi32lanes <-> b.lo32lanes
  asm("v_permlane32_swap_b32 %0, %1" : "+v"(a), "+v"(b));
}

DEV void async_ld16(const unsigned short* gsrc, unsigned short* lbase, int lane) {
#if __has_builtin(__builtin_amdgcn_global_load_lds)
  __builtin_amdgcn_global_load_lds(
      (const __attribute__((address_space(1))) unsigned int*)(const void*)gsrc,
      (__attribute__((address_space(3))) unsigned int*)(void*)lbase, 16, 0, 0);
#else
  *reinterpret_cast<u32x4v*>(reinterpret_cast<char*>(lbase) + lane * 16) =
      *reinterpret_cast<const u32x4v*>(gsrc);
#endif
}

// ---------- fp32 -> bf16 convert (single merged launch) ----------

DEV void cvt_body(const float* __restrict__ src, unsigned short* __restrict__ dst, int i) {
  const float4* s = reinterpret_cast<const float4*>(src) + (size_t)i * 2;
  float4 a = s[0], c = s[1];
  u16x4 lo = {f2bf(a.x), f2bf(a.y), f2bf(a.z), f2bf(a.w)};
  u16x4 hi = {f2bf(c.x), f2bf(c.y), f2bf(c.z), f2bf(c.w)};
  u16x4* d = reinterpret_cast<u16x4*>(dst) + (size_t)i * 2;
  d[0] = lo;
  d[1] = hi;
}

__global__ __launch_bounds__(256) void cvt_all(
    const float* __restrict__ q, const float* __restrict__ k, const float* __restrict__ v,
    const float* __restrict__ Wq, const float* __restrict__ Wk, const float* __restrict__ Wv,
    const float* __restrict__ Wo, unsigned short* dq, unsigned short* dk, unsigned short* dv,
    unsigned short* dWq, unsigned short* dWk, unsigned short* dWv, unsigned short* dWo) {
  const int bid = blockIdx.x;
  const float* src;
  unsigned short* dst;
  int i;
  if (bid < 6144) {
    const int z = bid >> 11;
    src = z == 0 ? q : z == 1 ? k : v;
    dst = z == 0 ? dq : z == 1 ? dk : dv;
    i = (bid & 2047) * 256 + threadIdx.x;
  } else {
    const int z = (bid - 6144) >> 9;
    src = z == 0 ? Wq : z == 1 ? Wk : z == 2 ? Wv : Wo;
    dst = z == 0 ? dWq : z == 1 ? dWk : z == 2 ? dWv : dWo;
    i = ((bid - 6144) & 511) * 256 + threadIdx.x;
  }
  cvt_body(src, dst, i);
}

// ---------- 128x128-tile GEMM core, BK=64, 2-phase dbuf (R5-proven, 45.5us) ----------

DEV void stage_b128(const unsigned short* __restrict__ G, int row0, int k0,
                    unsigned short* lbuf, int lane, int wv) {
#pragma unroll
  for (int r = 0; r < 4; ++r) {
    const int rowB = (r * 4 + wv) * 8 + (lane >> 3);
    const int chunk = (lane & 7) ^ (rowB & 7);
    async_ld16(G + (size_t)(row0 + rowB) * 1024 + k0 + chunk * 8, lbuf + (r * 4 + wv) * 512,
               lane);
  }
}

DEV void mfma_step(const unsigned short* lA, const unsigned short* lB, int lane, int wm, int wn,
                   f32x4 acc[4][4]) {
#pragma unroll
  for (int kk = 0; kk < 2; ++kk) {
    bf16x8 af[4], bfr[4];
#pragma unroll
    for (int f = 0; f < 4; ++f) {
      const int rowA = wm * 64 + f * 16 + (lane & 15);
      const int cA = (kk * 4 + (lane >> 4)) ^ (rowA & 7);
      af[f] = *reinterpret_cast<const bf16x8*>(lA + rowA * 64 + cA * 8);
      const int rowB = wn * 64 + f * 16 + (lane & 15);
      const int cB = (kk * 4 + (lane >> 4)) ^ (rowB & 7);
      bfr[f] = *reinterpret_cast<const bf16x8*>(lB + rowB * 64 + cB * 8);
    }
#pragma unroll
    for (int i = 0; i < 4; ++i)
#pragma unroll
      for (int j = 0; j < 4; ++j)
        acc[i][j] = __builtin_amdgcn_mfma_f32_16x16x32_bf16(af[i], bfr[j], acc[i][j], 0, 0, 0);
  }
}

DEV void gemm_core(const unsigned short* __restrict__ X, const unsigned short* __restrict__ W,
                   unsigned short* lA0, unsigned short* lA1, unsigned short* lB0,
                   unsigned short* lB1, int bm0, int bn0, int lane, int wv, int wm, int wn,
                   f32x4 acc[4][4]) {
  stage_b128(X, bm0, 0, lA0, lane, wv);
  stage_b128(W, bn0, 0, lB0, lane, wv);
  __syncthreads();  // drain prologue loads
  for (int kt = 0; kt < 16; ++kt) {
    unsigned short* lA = (kt & 1) ? lA1 : lA0;
    unsigned short* lB = (kt & 1) ? lB1 : lB0;
    unsigned short* nA = (kt & 1) ? lA0 : lA1;
    unsigned short* nB = (kt & 1) ? lB0 : lB1;
    if (kt < 15) {  // issue next-tile loads EARLY; they drain at this step's barrier
      stage_b128(X, bm0, (kt + 1) * 64, nA, lane, wv);
      stage_b128(W, bn0, (kt + 1) * 64, nB, lane, wv);
    }
    mfma_step(lA, lB, lane, wm, wn, acc);  // HBM latency hides under this
    __syncthreads();                       // prefetch drained; buffers safe to swap
  }
}

// ---------- QKV projection; Q,K -> [B,H,S,dk]; V -> TRANSPOSED [B,H,dk,S] ----------
// K-head-norm maxes folded into the epilogue (z==1): wave's 64 cols = one head.

__global__ __launch_bounds__(256) void gemm_qkv_kernel(
    const unsigned short* __restrict__ Xq, const unsigned short* __restrict__ Xk,
    const unsigned short* __restrict__ Xv, const unsigned short* __restrict__ Wq,
    const unsigned short* __restrict__ Wk, const unsigned short* __restrict__ Wv,
    const float* __restrict__ bq, const float* __restrict__ bk, const float* __restrict__ bv,
    unsigned short* __restrict__ Qp, unsigned short* __restrict__ Kp,
    unsigned short* __restrict__ Vp, unsigned* __restrict__ nb2) {
  __shared__ unsigned short lA[2][8192];
  __shared__ unsigned short lB[2][8192];
  const unsigned short* X;
  const unsigned short* W;
  const float* bias;
  unsigned short* dst;
  if (blockIdx.z == 0) { X = Xq; W = Wq; bias = bq; dst = Qp; }
  else if (blockIdx.z == 1) { X = Xk; W = Wk; bias = bk; dst = Kp; }
  else { X = Xv; W = Wv; bias = bv; dst = Vp; }
  const bool zV = (blockIdx.z == 2);
  const bool zK = (blockIdx.z == 1) && (nb2 != nullptr);
  const int lane = threadIdx.x & 63, wv = threadIdx.x >> 6;
  const int wm = wv >> 1, wn = wv & 1;
  const int bm0 = blockIdx.x * 128, bn0 = blockIdx.y * 128;
  f32x4 acc[4][4] = {};
  gemm_core(X, W, lA[0], lA[1], lB[0], lB[1], bm0, bn0, lane, wv, wm, wn, acc);
  float rowmax = 0.0f;
#pragma unroll
  for (int i = 0; i < 4; ++i) {
    const int mbase = bm0 + wm * 64 + i * 16 + ((lane >> 4) << 2);
#pragma unroll
    for (int r = 0; r < 4; ++r) {
      const int m = mbase + r;
      const int b = m >> 11, s = m & 2047;
      float ssp = 0.0f;
#pragma unroll
      for (int j = 0; j < 4; ++j) {
        const int n = bn0 + wn * 64 + j * 16 + (lane & 15);
        const float val = acc[i][j][r] + bias[n];
        const unsigned short v16 = f2bf(val);
        const int h = n >> 6, d = n & 63;
        if (zV)
          dst[((size_t)(b * 16 + h) * 64 + d) * 2048 + s] = v16;
        else
          dst[((size_t)(b * 16 + h) * 2048 + s) * 64 + d] = v16;
        ssp = __builtin_fmaf(val, val, ssp);
      }
      if (zK) {  // row norm^2 over this wave's head (64 cols across lane&15, j)
        ssp += __shfl_xor(ssp, 1);
        ssp += __shfl_xor(ssp, 2);
        ssp += __shfl_xor(ssp, 4);
        ssp += __shfl_xor(ssp, 8);
        rowmax = fmaxf(rowmax, ssp);
      }
    }
  }
  if (zK) {
    rowmax = fmaxf(rowmax, __shfl_xor(rowmax, 16));
    rowmax = fmaxf(rowmax, __shfl_xor(rowmax, 32));
    if (lane == 0) {
      const int bh = (bm0 >> 11) * 16 + blockIdx.y * 2 + wn;
      atomicMax(nb2 + bh, __float_as_uint(rowmax));
    }
  }
}

// ---------- output projection ----------

__global__ __launch_bounds__(256) void gemm_out_kernel(const unsigned short* __restrict__ X,
                                                       const unsigned short* __restrict__ W,
                                                       const float* __restrict__ bias,
                                                       float* __restrict__ out) {
  __shared__ unsigned short lA[2][8192];
  __shared__ unsigned short lB[2][8192];
  const int lane = threadIdx.x & 63, wv = threadIdx.x >> 6;
  const int wm = wv >> 1, wn = wv & 1;
  const int bm0 = blockIdx.x * 128, bn0 = blockIdx.y * 128;
  f32x4 acc[4][4] = {};
  gemm_core(X, W, lA[0], lA[1], lB[0], lB[1], bm0, bn0, lane, wv, wm, wn, acc);
#pragma unroll
  for (int i = 0; i < 4; ++i) {
    const int mbase = bm0 + wm * 64 + i * 16 + ((lane >> 4) << 2);
#pragma unroll
    for (int j = 0; j < 4; ++j) {
      const int n = bn0 + wn * 64 + j * 16 + (lane & 15);
      const float bia = bias[n];
#pragma unroll
      for (int r = 0; r < 4; ++r) out[(size_t)(mbase + r) * 1024 + n] = acc[i][j][r] + bia;
    }
  }
}

// ---------- K-norm fallback (compact-ws only): nb2[bh] = max_s ||k_s||^2 ----------

__global__ __launch_bounds__(256) void knorm_kernel(const unsigned short* __restrict__ Kp,
                                                    unsigned* __restrict__ nb2) {
  const int bh = blockIdx.y;
  const int s = blockIdx.x * 256 + threadIdx.x;
  const u32x4v* row = reinterpret_cast<const u32x4v*>(Kp + ((size_t)bh * 2048 + s) * 64);
  float ss = 0.0f;
#pragma unroll
  for (int c = 0; c < 8; ++c) {
    u32x4v u = row[c];
#pragma unroll
    for (int e = 0; e < 4; ++e) {
      const float lo = __builtin_bit_cast(float, u[e] << 16);
      const float hi = __builtin_bit_cast(float, u[e] & 0xFFFF0000u);
      ss = __builtin_fmaf(lo, lo, ss);
      ss = __builtin_fmaf(hi, hi, ss);
    }
  }
#pragma unroll
  for (int off = 1; off <= 32; off <<= 1) ss = fmaxf(ss, __shfl_xor(ss, off));
  if ((threadIdx.x & 63) == 0) atomicMax(nb2 + bh, __float_as_uint(ss));
}

// ---------- prepass: per (bh, qt64): m_floor (tile-0 row-max min, j-domain) + blt ----------

__global__ __launch_bounds__(128) void attn_prepass(const unsigned short* __restrict__ Qp,
                                                    const unsigned short* __restrict__ Kp,
                                                    const unsigned* __restrict__ nb2,
                                                    float* __restrict__ mfA,
                                                    float* __restrict__ bltA) {
  __shared__ float sred[4];
  const int lane = threadIdx.x & 63, wv = threadIdx.x >> 6;
  const int lq = lane & 31, hi = lane >> 5;
  const int qt = blockIdx.x, bh = blockIdx.y, h = bh & 15;
  const float L2E = 1.4426950408889634f;
  const float slope2 = ldexpf(L2E, h - 8);
  const float SC2 = 0.125f * L2E;
  const size_t headoff = (size_t)bh * 2048 * 64;
  const unsigned short* Qh = Qp + headoff;
  const unsigned short* Kh = Kp + headoff;
  const int q_glob = qt * 64 + wv * 32 + lq;

  bf16x8 qf[4];
#pragma unroll
  for (int tt = 0; tt < 4; ++tt)
    qf[tt] = *reinterpret_cast<const bf16x8*>(Qh + (size_t)q_glob * 64 + tt * 16 + hi * 8);

  float qq = 0.0f;
#pragma unroll
  for (int tt = 0; tt < 4; ++tt)
#pragma unroll
    for (int e = 0; e < 8; ++e) {
      const float x = (float)qf[tt][e];
      qq = __builtin_fmaf(x, x, qq);
    }
  qq += __shfl_xor(qq, 32);
#pragma unroll
  for (int off = 1; off <= 16; off <<= 1) qq = fmaxf(qq, __shfl_xor(qq, off));

  f32x16 s0 = {}, s1 = {};
#pragma unroll
  for (int tt = 0; tt < 4; ++tt) {
    bf16x8 k0 = *reinterpret_cast<const bf16x8*>(Kh + (size_t)lq * 64 + tt * 16 + hi * 8);
    s0 = __builtin_amdgcn_mfma_f32_32x32x16_bf16(k0, qf[tt], s0, 0, 0, 0);
    bf16x8 k1 = *reinterpret_cast<const bf16x8*>(Kh + (size_t)(32 + lq) * 64 + tt * 16 + hi * 8);
    s1 = __builtin_amdgcn_mfma_f32_32x32x16_bf16(k1, qf[tt], s1, 0, 0, 0);
  }
  float zmax = -3.0e38f;
#pragma unroll
  for (int r = 0; r < 16; ++r) {
    const float cb = -slope2 * (float)(4 * hi + (r & 3) + 8 * (r >> 2));
    const float x0 = __builtin_fmaf(s0[r], SC2, cb);
    const float x1 = __builtin_fmaf(s1[r], SC2, cb - slope2 * 32.0f);
    zmax = fmaxf(zmax, fmaxf(x0, x1));
  }
  zmax = fmaxf(zmax, __shfl_xor(zmax, 32));
  float zmin = zmax;
#pragma unroll
  for (int off = 1; off <= 16; off <<= 1) zmin = fminf(zmin, __shfl_xor(zmin, off));
  if (lane == 0) {
    sred[wv] = zmin;
    sred[2 + wv] = qq;
  }
  __syncthreads();
  if (threadIdx.x == 0) {
    const float mf = fminf(sred[0], sred[1]);
    const float qn = sqrtf(fmaxf(sred[2], sred[3]));
    const float nk = sqrtf(__uint_as_float(nb2[bh]));
    mfA[bh * 32 + qt] = mf;
    bltA[bh * 32 + qt] = qn * nk * SC2;
  }
}

// ---------- flash attention KV-split: partial (m,l,O) per (bh,qt,split) ----------

DEV void stage_tile64(const unsigned short* __restrict__ Gbase, size_t stride, int colbase,
                      unsigned short* lbuf, int lane, int wv) {
#pragma unroll
  for (int i = 0; i < 4; ++i) {
    const int r = i * 16 + wv * 8 + (lane >> 3);
    const int chunk = (lane & 7) ^ (r & 7);
    async_ld16(Gbase + (size_t)r * stride + colbase + chunk * 8, lbuf + (i * 16 + wv * 8) * 64,
               lane);
  }
}

__global__ __launch_bounds__(128) void attn_split_kernel(
    const unsigned short* __restrict__ Qp, const unsigned short* __restrict__ Kp,
    const unsigned short* __restrict__ VTp, const float* __restrict__ mfA,
    const float* __restrict__ bltA, float* __restrict__ ML, float* __restrict__ Opart, int Ct,
    int nsplit) {
  __shared__ unsigned short Kb[2][64 * 64];
  __shared__ unsigned short Vb[2][64 * 64];
  const int lane = threadIdx.x & 63, wv = threadIdx.x >> 6;
  const int lq = lane & 31, hi = lane >> 5;
  const int qt = blockIdx.x, sp = blockIdx.y, bh = blockIdx.z;
  const int h = bh & 15;
  const int idx = bh * 32 + qt;
  const float L2E = 1.4426950408889634f;
  const float slope2 = ldexpf(L2E, h - 8);
  const float SC2 = 0.125f * L2E;
  const float m_floor = mfA[idx], blt = bltA[idx];
  const float tf = (blt - m_floor + 34.0f) / (slope2 * 64.0f);
  const int T_act = min(32, (int)tf + 1);
  const int t0 = sp * Ct;
  const int nt = min(Ct, T_act - t0);
  float* mlb = ML + ((size_t)idx * nsplit + sp) * 128;
  if (nt <= 0) {  // inactive split: sentinel only
    mlb[threadIdx.x] = threadIdx.x < 64 ? -3.0e38f : 0.0f;
    return;
  }
  float* ob = Opart + ((size_t)idx * nsplit + sp) * 4096;
  const size_t headoff = (size_t)bh * 2048 * 64;
  const unsigned short* Qh = Qp + headoff;
  const unsigned short* Kh = Kp + headoff;
  const unsigned short* VTh = VTp + headoff;
  const int q_glob = qt * 64 + wv * 32 + lq;

  float cb0[16], cb1[16];
#pragma unroll
  for (int r = 0; r < 16; ++r) {
    cb0[r] = -slope2 * (float)(4 * hi + (r & 3) + 8 * (r >> 2));
    cb1[r] = cb0[r] - slope2 * 32.0f;
  }

  bf16x8 qf[4];
#pragma unroll
  for (int tt = 0; tt < 4; ++tt)
    qf[tt] = *reinterpret_cast<const bf16x8*>(Qh + (size_t)q_glob * 64 + tt * 16 + hi * 8);

  stage_tile64(Kh + (size_t)(t0 * 64) * 64, 64, 0, Kb[0], lane, wv);
  stage_tile64(VTh, 2048, t0 * 64, Vb[0], lane, wv);
  __syncthreads();

  f32x16 acc0 = {}, acc1 = {};
  float m_run = m_floor, l_run = 0.0f;

  for (int ti = 0; ti < nt; ++ti) {
    const int kv0 = (t0 + ti) * 64;
    const float s2k = slope2 * (float)kv0;
    const unsigned short* Kc = Kb[ti & 1];
    const unsigned short* Vc = Vb[ti & 1];
    if (ti + 1 < nt) {
      stage_tile64(Kh + (size_t)(kv0 + 64) * 64, 64, 0, Kb[(ti + 1) & 1], lane, wv);
      stage_tile64(VTh, 2048, kv0 + 64, Vb[(ti + 1) & 1], lane, wv);
    }
    f32x16 s0 = {}, s1 = {};
    __builtin_amdgcn_s_setprio(1);
#pragma unroll
    for (int tt = 0; tt < 4; ++tt) {
      {
        const int row = lq;
        const int ch = (tt * 2 + hi) ^ (row & 7);
        bf16x8 kf = *reinterpret_cast<const bf16x8*>(Kc + row * 64 + ch * 8);
        s0 = __builtin_amdgcn_mfma_f32_32x32x16_bf16(kf, qf[tt], s0, 0, 0, 0);
      }
      {
        const int row = 32 + lq;
        const int ch = (tt * 2 + hi) ^ (row & 7);
        bf16x8 kf = *reinterpret_cast<const bf16x8*>(Kc + row * 64 + ch * 8);
        s1 = __builtin_amdgcn_mfma_f32_32x32x16_bf16(kf, qf[tt], s1, 0, 0, 0);
      }
    }
    __builtin_amdgcn_s_setprio(0);
    float zmax = -3.0e38f;
#pragma unroll
    for (int r = 0; r < 16; ++r) {
      s0[r] = __builtin_fmaf(s0[r], SC2, cb0[r]);
      s1[r] = __builtin_fmaf(s1[r], SC2, cb1[r]);
      zmax = fmaxf(zmax, fmaxf(s0[r], s1[r]));
    }
    zmax = fmaxf(zmax, __shfl_xor(zmax, 32));
    const float tmax_true = zmax - s2k;
    if (__any(tmax_true > m_run + 8.0f)) {  // defer-max
      const float m_new = fmaxf(m_run, tmax_true);
      const float alpha = fexp2(m_run - m_new);
      m_run = m_new;
      l_run *= alpha;
      acc0 *= alpha;
      acc1 *= alpha;
    }
    const float mm = m_run + s2k;
    float ps0 = 0.0f, ps1 = 0.0f;
#pragma unroll
    for (int r = 0; r < 16; ++r) {
      const float p0 = fexp2(s0[r] - mm);
      const float p1 = fexp2(s1[r] - mm);
      s0[r] = p0;
      s1[r] = p1;
      ps0 += p0;
      ps1 += p1;
    }
    float psum = ps0 + ps1;
    psum += __shfl_xor(psum, 32);
    l_run += psum;
    bf16x8 pf[4];
#pragma unroll
    for (int half = 0; half < 2; ++half) {
      u32 w0 = cvtpk(s0[half * 8 + 0], s0[half * 8 + 1]);
      u32 w2 = cvtpk(s0[half * 8 + 4], s0[half * 8 + 5]);
      plswap(w0, w2);
      u32 w1 = cvtpk(s0[half * 8 + 2], s0[half * 8 + 3]);
      u32 w3 = cvtpk(s0[half * 8 + 6], s0[half * 8 + 7]);
      plswap(w1, w3);
      u32x4v ww = {w0, w1, w2, w3};
      pf[half] = __builtin_bit_cast(bf16x8, ww);
    }
#pragma unroll
    for (int half = 0; half < 2; ++half) {
      u32 w0 = cvtpk(s1[half * 8 + 0], s1[half * 8 + 1]);
      u32 w2 = cvtpk(s1[half * 8 + 4], s1[half * 8 + 5]);
      plswap(w0, w2);
      u32 w1 = cvtpk(s1[half * 8 + 2], s1[half * 8 + 3]);
      u32 w3 = cvtpk(s1[half * 8 + 6], s1[half * 8 + 7]);
      plswap(w1, w3);
      u32x4v ww = {w0, w1, w2, w3};
      pf[2 + half] = __builtin_bit_cast(bf16x8, ww);
    }
    __builtin_amdgcn_s_setprio(1);
#pragma unroll
    for (int tt = 0; tt < 4; ++tt) {
      {
        const int row = lq;
        const int ch = (tt * 2 + hi) ^ (row & 7);
        bf16x8 vf = *reinterpret_cast<const bf16x8*>(Vc + row * 64 + ch * 8);
        acc0 = __builtin_amdgcn_mfma_f32_32x32x16_bf16(vf, pf[tt], acc0, 0, 0, 0);
      }
      {
        const int row = 32 + lq;
        const int ch = (tt * 2 + hi) ^ (row & 7);
        bf16x8 vf = *reinterpret_cast<const bf16x8*>(Vc + row * 64 + ch * 8);
        acc1 = __builtin_amdgcn_mfma_f32_32x32x16_bf16(vf, pf[tt], acc1, 0, 0, 0);
      }
    }
    __builtin_amdgcn_s_setprio(0);
    __syncthreads();
  }
  const int qloc = wv * 32 + lq;
  if (hi == 0) {
    mlb[qloc] = m_run;
    mlb[64 + qloc] = l_run;
  }
#pragma unroll
  for (int g = 0; g < 4; ++g) {
    f32x4 w0, w1;
#pragma unroll
    for (int e = 0; e < 4; ++e) {
      w0[e] = acc0[g * 4 + e];
      w1[e] = acc1[g * 4 + e];
    }
    *reinterpret_cast<f32x4*>(ob + qloc * 64 + g * 8 + 4 * hi) = w0;
    *reinterpret_cast<f32x4*>(ob + qloc * 64 + 32 + g * 8 + 4 * hi) = w1;
  }
}

// ---------- combine partials -> Obf bf16 [B,S,H*64] ----------

__global__ __launch_bounds__(256) void attn_combine(const float* __restrict__ ML,
                                                    const float* __restrict__ Opart,
                                                    unsigned short* __restrict__ Ob, int nsplit) {
  const int idx = blockIdx.x;  // bh*32 + qt
  const int bh = idx >> 5, qt = idx & 31;
  const int h = bh & 15, b = bh >> 4;
  const int q = threadIdx.x >> 2, d0 = (threadIdx.x & 3) * 16;
  const float* mlb = ML + (size_t)idx * nsplit * 128;
  const float* ob = Opart + (size_t)idx * nsplit * 4096;
  float m_g = -3.0e38f;
  for (int s = 0; s < nsplit; ++s) m_g = fmaxf(m_g, mlb[s * 128 + q]);
  float l = 0.0f;
  f32x4 acc[4] = {};
  for (int s = 0; s < nsplit; ++s) {
    const float ms = mlb[s * 128 + q], ls = mlb[s * 128 + 64 + q];
    const float w = fexp2(ms - m_g);
    const float wl = w * ls;
    if (wl > 0.0f) {
      l += wl;
      const f32x4* src = reinterpret_cast<const f32x4*>(ob + (size_t)s * 4096 + q * 64 + d0);
#pragma unroll
      for (int j = 0; j < 4; ++j) {
        f32x4 v = src[j];
#pragma unroll
        for (int e = 0; e < 4; ++e) acc[j][e] = __builtin_fmaf(w, v[e], acc[j][e]);
      }
    }
  }
  const float invl = 1.0f / l;
  unsigned short* orow = Ob + ((size_t)(b * 2048 + qt * 64 + q)) * 1024 + h * 64 + d0;
#pragma unroll
  for (int j = 0; j < 4; ++j) {
    u16x4 pk;
#pragma unroll
    for (int e = 0; e < 4; ++e) pk[e] = f2bf(acc[j][e] * invl);
    *reinterpret_cast<u16x4*>(orow + j * 4) = pk;
  }
}

// ---------- launcher ----------

extern "C" void kernel_launch(void* const* d_in, const int* in_sizes, int n_in, void* d_out,
                              int out_size, void* d_ws, size_t ws_size, hipStream_t stream) {
  const float* q = (const float*)d_in[0];
  const float* k = (const float*)d_in[1];
  const float* v = (const float*)d_in[2];
  const float* Wq = (const float*)d_in[3];
  const float* bq = (const float*)d_in[4];
  const float* Wk = (const float*)d_in[5];
  const float* bk = (const float*)d_in[6];
  const float* Wv = (const float*)d_in[7];
  const float* bv = (const float*)d_in[8];
  const float* Wo = (const float*)d_in[9];
  const float* bo = (const float*)d_in[10];

  char* ws = (char*)d_ws;
  const size_t MB = 1024 * 1024;
  unsigned short* qb = (unsigned short*)(ws + 0 * MB);    // dead after gemm_qkv
  unsigned short* kb = (unsigned short*)(ws + 8 * MB);    // dead after gemm_qkv
  unsigned short* vb = (unsigned short*)(ws + 16 * MB);   // dead after gemm_qkv
  unsigned short* Wqb = (unsigned short*)(ws + 24 * MB);  // dead after gemm_qkv
  unsigned short* Wkb = (unsigned short*)(ws + 26 * MB);  // dead after gemm_qkv
  unsigned short* Wvb = (unsigned short*)(ws + 28 * MB);  // dead after gemm_qkv
  unsigned short* Wob = (unsigned short*)(ws + 30 * MB);  // LIVE until gemm_out
  unsigned short* Qp = (unsigned short*)(ws + 32 * MB);
  unsigned short* Kp = (unsigned short*)(ws + 40 * MB);
  unsigned short* VTp = (unsigned short*)(ws + 48 * MB);
  unsigned short* Obf = (unsigned short*)(ws + 0 * MB);  // reuse qb

  int nsplit;
  float *mfA, *bltA, *ML, *Opart;
  unsigned* nb2;
  bool fold_knorm;
  if (ws_size >= (size_t)121 * MB) nsplit = 4;
  else if (ws_size >= (size_t)89 * MB) nsplit = 2;
  else nsplit = 1;
  if (ws_size >= (size_t)73 * MB) {
    fold_knorm = true;
    nb2 = (unsigned*)(ws + 56 * MB);      // beyond all gemm I/O: safe for in-gemm atomics
    mfA = (float*)(ws + 24 * MB + 4096);  // written post-gemm (Wqb dead then)
    bltA = (float*)(ws + 24 * MB + 8192);
    ML = (float*)(ws + 26 * MB + 65536);  // Wkb dead post-gemm
    Opart = (float*)(ws + 56 * MB + 4096);
  } else {
    fold_knorm = false;
    nsplit = 1;
    nb2 = (unsigned*)(ws + 26 * MB);  // Wkb region, written only AFTER gemm (knorm kernel)
    mfA = (float*)(ws + 26 * MB + 4096);
    bltA = (float*)(ws + 26 * MB + 8192);
    ML = (float*)(ws + 26 * MB + 65536);
    Opart = (float*)(ws + 8 * MB);
  }
  const int Ct = 32 / nsplit;

  cvt_all<<<8192, 256, 0, stream>>>(q, k, v, Wq, Wk, Wv, Wo, qb, kb, vb, Wqb, Wkb, Wvb, Wob);
  hipMemsetAsync(nb2, 0, 64 * sizeof(unsigned), stream);
  gemm_qkv_kernel<<<dim3(32, 8, 3), 256, 0, stream>>>(qb, kb, vb, Wqb, Wkb, Wvb, bq, bk, bv, Qp,
                                                      Kp, VTp, fold_knorm ? nb2 : nullptr);
  if (!fold_knorm) knorm_kernel<<<dim3(8, 32), 256, 0, stream>>>(Kp, nb2);
  attn_prepass<<<dim3(32, 32), 128, 0, stream>>>(Qp, Kp, nb2, mfA, bltA);
  attn_split_kernel<<<dim3(32, nsplit, 32), 128, 0, stream>>>(Qp, Kp, VTp, mfA, bltA, ML, Opart,
                                                              Ct, nsplit);
  attn_combine<<<1024, 256, 0, stream>>>(ML, Opart, Obf, nsplit);
  gemm_out_kernel<<<dim3(32, 8), 256, 0, stream>>>(Obf, Wob, bo, (float*)d_out);
}

// Round 10
// 124.353 us; speedup vs baseline: 1.2130x; 1.0021x over previous
//
#include <hip/hip_runtime.h>

typedef __bf16 bf16_t;
typedef bf16_t bf16x8 __attribute__((ext_vector_type(8)));
typedef float f32x4 __attribute__((ext_vector_type(4)));
typedef float f32x16 __attribute__((ext_vector_type(16)));
typedef unsigned short u16x4 __attribute__((ext_vector_type(4)));
typedef unsigned int u32x4v __attribute__((ext_vector_type(4)));
typedef unsigned int u32;

#define DEV static __device__ __forceinline__

// ---------- helpers ----------

DEV unsigned short f2bf(float f) {
  unsigned int u = __builtin_bit_cast(unsigned int, f);
  u = (u + 0x7fffu + ((u >> 16) & 1u)) >> 16;  // RNE
  return (unsigned short)u;
}

DEV float fexp2(float x) {  // 2^x via v_exp_f32
  float r;
  asm("v_exp_f32 %0, %1" : "=v"(r) : "v"(x));
  return r;
}

DEV u32 cvtpk(float lo, float hi_) {  // packed bf16 pair (RNE)
  u32 r;
  asm("v_cvt_pk_bf16_f32 %0, %1, %2" : "=v"(r) : "v"(lo), "v"(hi_));
  return r;
}

DEV void plswap(u32& a, u32& b) {  // swap a.hi32lanes <-> b.lo32lanes
  asm("v_permlane32_swap_b32 %0, %1" : "+v"(a), "+v"(b));
}

DEV void async_ld16(const unsigned short* gsrc, unsigned short* lbase, int lane) {
#if __has_builtin(__builtin_amdgcn_global_load_lds)
  __builtin_amdgcn_global_load_lds(
      (const __attribute__((address_space(1))) unsigned int*)(const void*)gsrc,
      (__attribute__((address_space(3))) unsigned int*)(void*)lbase, 16, 0, 0);
#else
  *reinterpret_cast<u32x4v*>(reinterpret_cast<char*>(lbase) + lane * 16) =
      *reinterpret_cast<const u32x4v*>(gsrc);
#endif
}

// ---------- fp32 -> bf16 convert (single merged launch; also zeroes nb2) ----------

DEV void cvt_body(const float* __restrict__ src, unsigned short* __restrict__ dst, int i) {
  const float4* s = reinterpret_cast<const float4*>(src) + (size_t)i * 2;
  float4 a = s[0], c = s[1];
  u16x4 lo = {f2bf(a.x), f2bf(a.y), f2bf(a.z), f2bf(a.w)};
  u16x4 hi = {f2bf(c.x), f2bf(c.y), f2bf(c.z), f2bf(c.w)};
  u16x4* d = reinterpret_cast<u16x4*>(dst) + (size_t)i * 2;
  d[0] = lo;
  d[1] = hi;
}

__global__ __launch_bounds__(256) void cvt_all(
    const float* __restrict__ q, const float* __restrict__ k, const float* __restrict__ v,
    const float* __restrict__ Wq, const float* __restrict__ Wk, const float* __restrict__ Wv,
    const float* __restrict__ Wo, unsigned short* dq, unsigned short* dk, unsigned short* dv,
    unsigned short* dWq, unsigned short* dWk, unsigned short* dWv, unsigned short* dWo,
    unsigned* __restrict__ nb2z) {
  const int bid = blockIdx.x;
  if (nb2z != nullptr && bid == 0 && threadIdx.x < 64) nb2z[threadIdx.x] = 0u;
  const float* src;
  unsigned short* dst;
  int i;
  if (bid < 6144) {
    const int z = bid >> 11;
    src = z == 0 ? q : z == 1 ? k : v;
    dst = z == 0 ? dq : z == 1 ? dk : dv;
    i = (bid & 2047) * 256 + threadIdx.x;
  } else {
    const int z = (bid - 6144) >> 9;
    src = z == 0 ? Wq : z == 1 ? Wk : z == 2 ? Wv : Wo;
    dst = z == 0 ? dWq : z == 1 ? dWk : z == 2 ? dWv : dWo;
    i = ((bid - 6144) & 511) * 256 + threadIdx.x;
  }
  cvt_body(src, dst, i);
}

// ---------- 128x128-tile GEMM core, BK=64, 2-phase dbuf, hoisted addressing ----------
// Per-lane global pointers computed once; fully-unrolled K-loop folds kt*128B into
// the global_load_lds offset field -> ~zero per-step address VALU.

DEV void mfma_step(const unsigned short* lA, const unsigned short* lB, int lane, int wm, int wn,
                   f32x4 acc[4][4]) {
#pragma unroll
  for (int kk = 0; kk < 2; ++kk) {
    bf16x8 af[4], bfr[4];
#pragma unroll
    for (int f = 0; f < 4; ++f) {
      const int rowA = wm * 64 + f * 16 + (lane & 15);
      const int cA = (kk * 4 + (lane >> 4)) ^ (rowA & 7);
      af[f] = *reinterpret_cast<const bf16x8*>(lA + rowA * 64 + cA * 8);
      const int rowB = wn * 64 + f * 16 + (lane & 15);
      const int cB = (kk * 4 + (lane >> 4)) ^ (rowB & 7);
      bfr[f] = *reinterpret_cast<const bf16x8*>(lB + rowB * 64 + cB * 8);
    }
#pragma unroll
    for (int i = 0; i < 4; ++i)
#pragma unroll
      for (int j = 0; j < 4; ++j)
        acc[i][j] = __builtin_amdgcn_mfma_f32_16x16x32_bf16(af[i], bfr[j], acc[i][j], 0, 0, 0);
  }
}

DEV void gemm_core(const unsigned short* __restrict__ X, const unsigned short* __restrict__ W,
                   unsigned short* lA0, unsigned short* lA1, unsigned short* lB0,
                   unsigned short* lB1, int bm0, int bn0, int lane, int wv, int wm, int wn,
                   f32x4 acc[4][4]) {
  // hoisted per-lane staging sources (XOR-swizzled chunk on the global side)
  const unsigned short* pa[4];
  const unsigned short* pb[4];
#pragma unroll
  for (int r = 0; r < 4; ++r) {
    const int row = (r * 4 + wv) * 8 + (lane >> 3);
    const int chunk = (lane & 7) ^ (row & 7);
    pa[r] = X + (size_t)(bm0 + row) * 1024 + chunk * 8;
    pb[r] = W + (size_t)(bn0 + row) * 1024 + chunk * 8;
  }
#pragma unroll
  for (int r = 0; r < 4; ++r) {
    async_ld16(pa[r], lA0 + (r * 4 + wv) * 512, lane);
    async_ld16(pb[r], lB0 + (r * 4 + wv) * 512, lane);
  }
  __syncthreads();  // drain prologue loads
#pragma unroll
  for (int kt = 0; kt < 16; ++kt) {
    const unsigned short* lA = (kt & 1) ? lA1 : lA0;
    const unsigned short* lB = (kt & 1) ? lB1 : lB0;
    unsigned short* nA = (kt & 1) ? lA0 : lA1;
    unsigned short* nB = (kt & 1) ? lB0 : lB1;
    if (kt < 15) {  // issue next-tile loads EARLY; constant offset folds into insn
#pragma unroll
      for (int r = 0; r < 4; ++r) {
        async_ld16(pa[r] + (kt + 1) * 64, nA + (r * 4 + wv) * 512, lane);
        async_ld16(pb[r] + (kt + 1) * 64, nB + (r * 4 + wv) * 512, lane);
      }
    }
    mfma_step(lA, lB, lane, wm, wn, acc);  // HBM latency hides under this
    __syncthreads();                       // prefetch drained; buffers safe to swap
  }
}

// ---------- QKV projection; Q,K -> [B,H,S,dk]; V -> TRANSPOSED [B,H,dk,S] ----------
// K-head-norm maxes folded into the epilogue (z==1): wave's 64 cols = one head.

__global__ __launch_bounds__(256) void gemm_qkv_kernel(
    const unsigned short* __restrict__ Xq, const unsigned short* __restrict__ Xk,
    const unsigned short* __restrict__ Xv, const unsigned short* __restrict__ Wq,
    const unsigned short* __restrict__ Wk, const unsigned short* __restrict__ Wv,
    const float* __restrict__ bq, const float* __restrict__ bk, const float* __restrict__ bv,
    unsigned short* __restrict__ Qp, unsigned short* __restrict__ Kp,
    unsigned short* __restrict__ Vp, unsigned* __restrict__ nb2) {
  __shared__ unsigned short lA[2][8192];
  __shared__ unsigned short lB[2][8192];
  const unsigned short* X;
  const unsigned short* W;
  const float* bias;
  unsigned short* dst;
  if (blockIdx.z == 0) { X = Xq; W = Wq; bias = bq; dst = Qp; }
  else if (blockIdx.z == 1) { X = Xk; W = Wk; bias = bk; dst = Kp; }
  else { X = Xv; W = Wv; bias = bv; dst = Vp; }
  const bool zV = (blockIdx.z == 2);
  const bool zK = (blockIdx.z == 1) && (nb2 != nullptr);
  const int lane = threadIdx.x & 63, wv = threadIdx.x >> 6;
  const int wm = wv >> 1, wn = wv & 1;
  const int bm0 = blockIdx.x * 128, bn0 = blockIdx.y * 128;
  f32x4 acc[4][4] = {};
  gemm_core(X, W, lA[0], lA[1], lB[0], lB[1], bm0, bn0, lane, wv, wm, wn, acc);
  float rowmax = 0.0f;
#pragma unroll
  for (int i = 0; i < 4; ++i) {
    const int mbase = bm0 + wm * 64 + i * 16 + ((lane >> 4) << 2);
#pragma unroll
    for (int r = 0; r < 4; ++r) {
      const int m = mbase + r;
      const int b = m >> 11, s = m & 2047;
      float ssp = 0.0f;
#pragma unroll
      for (int j = 0; j < 4; ++j) {
        const int n = bn0 + wn * 64 + j * 16 + (lane & 15);
        const float val = acc[i][j][r] + bias[n];
        const unsigned short v16 = f2bf(val);
        const int h = n >> 6, d = n & 63;
        if (zV)
          dst[((size_t)(b * 16 + h) * 64 + d) * 2048 + s] = v16;
        else
          dst[((size_t)(b * 16 + h) * 2048 + s) * 64 + d] = v16;
        ssp = __builtin_fmaf(val, val, ssp);
      }
      if (zK) {  // row norm^2 over this wave's head (64 cols across lane&15, j)
        ssp += __shfl_xor(ssp, 1);
        ssp += __shfl_xor(ssp, 2);
        ssp += __shfl_xor(ssp, 4);
        ssp += __shfl_xor(ssp, 8);
        rowmax = fmaxf(rowmax, ssp);
      }
    }
  }
  if (zK) {
    rowmax = fmaxf(rowmax, __shfl_xor(rowmax, 16));
    rowmax = fmaxf(rowmax, __shfl_xor(rowmax, 32));
    if (lane == 0) {
      const int bh = (bm0 >> 11) * 16 + blockIdx.y * 2 + wn;
      atomicMax(nb2 + bh, __float_as_uint(rowmax));
    }
  }
}

// ---------- output projection ----------

__global__ __launch_bounds__(256) void gemm_out_kernel(const unsigned short* __restrict__ X,
                                                       const unsigned short* __restrict__ W,
                                                       const float* __restrict__ bias,
                                                       float* __restrict__ out) {
  __shared__ unsigned short lA[2][8192];
  __shared__ unsigned short lB[2][8192];
  const int lane = threadIdx.x & 63, wv = threadIdx.x >> 6;
  const int wm = wv >> 1, wn = wv & 1;
  const int bm0 = blockIdx.x * 128, bn0 = blockIdx.y * 128;
  f32x4 acc[4][4] = {};
  gemm_core(X, W, lA[0], lA[1], lB[0], lB[1], bm0, bn0, lane, wv, wm, wn, acc);
#pragma unroll
  for (int i = 0; i < 4; ++i) {
    const int mbase = bm0 + wm * 64 + i * 16 + ((lane >> 4) << 2);
#pragma unroll
    for (int j = 0; j < 4; ++j) {
      const int n = bn0 + wn * 64 + j * 16 + (lane & 15);
      const float bia = bias[n];
#pragma unroll
      for (int r = 0; r < 4; ++r) out[(size_t)(mbase + r) * 1024 + n] = acc[i][j][r] + bia;
    }
  }
}

// ---------- K-norm fallback (compact-ws only): nb2[bh] = max_s ||k_s||^2 ----------

__global__ __launch_bounds__(256) void knorm_kernel(const unsigned short* __restrict__ Kp,
                                                    unsigned* __restrict__ nb2) {
  const int bh = blockIdx.y;
  const int s = blockIdx.x * 256 + threadIdx.x;
  const u32x4v* row = reinterpret_cast<const u32x4v*>(Kp + ((size_t)bh * 2048 + s) * 64);
  float ss = 0.0f;
#pragma unroll
  for (int c = 0; c < 8; ++c) {
    u32x4v u = row[c];
#pragma unroll
    for (int e = 0; e < 4; ++e) {
      const float lo = __builtin_bit_cast(float, u[e] << 16);
      const float hi = __builtin_bit_cast(float, u[e] & 0xFFFF0000u);
      ss = __builtin_fmaf(lo, lo, ss);
      ss = __builtin_fmaf(hi, hi, ss);
    }
  }
#pragma unroll
  for (int off = 1; off <= 32; off <<= 1) ss = fmaxf(ss, __shfl_xor(ss, off));
  if ((threadIdx.x & 63) == 0) atomicMax(nb2 + bh, __float_as_uint(ss));
}

// ---------- flash attention KV-split with integrated prepass ----------
// Each (bh,qt,split) block computes its own m_floor (tile-0 row-max min, j-domain)
// and blt (Cauchy-Schwarz bound) -- bitwise-identical across split replicas.

DEV void stage_tile64(const unsigned short* __restrict__ Gbase, size_t stride, int colbase,
                      unsigned short* lbuf, int lane, int wv) {
#pragma unroll
  for (int i = 0; i < 4; ++i) {
    const int r = i * 16 + wv * 8 + (lane >> 3);
    const int chunk = (lane & 7) ^ (r & 7);
    async_ld16(Gbase + (size_t)r * stride + colbase + chunk * 8, lbuf + (i * 16 + wv * 8) * 64,
               lane);
  }
}

__global__ __launch_bounds__(128) void attn_split_kernel(
    const unsigned short* __restrict__ Qp, const unsigned short* __restrict__ Kp,
    const unsigned short* __restrict__ VTp, const unsigned* __restrict__ nb2,
    float* __restrict__ ML, float* __restrict__ Opart, int Ct, int nsplit) {
  __shared__ unsigned short Kb[2][64 * 64];
  __shared__ unsigned short Vb[2][64 * 64];
  __shared__ float sred[4];
  const int lane = threadIdx.x & 63, wv = threadIdx.x >> 6;
  const int lq = lane & 31, hi = lane >> 5;
  const int qt = blockIdx.x, sp = blockIdx.y, bh = blockIdx.z;
  const int h = bh & 15;
  const int idx = bh * 32 + qt;
  const float L2E = 1.4426950408889634f;
  const float slope2 = ldexpf(L2E, h - 8);
  const float SC2 = 0.125f * L2E;
  const int t0 = sp * Ct;
  float* mlb = ML + ((size_t)idx * nsplit + sp) * 128;
  const size_t headoff = (size_t)bh * 2048 * 64;
  const unsigned short* Qh = Qp + headoff;
  const unsigned short* Kh = Kp + headoff;
  const unsigned short* VTh = VTp + headoff;
  const int q_glob = qt * 64 + wv * 32 + lq;

  float cb0[16], cb1[16];
#pragma unroll
  for (int r = 0; r < 16; ++r) {
    cb0[r] = -slope2 * (float)(4 * hi + (r & 3) + 8 * (r >> 2));
    cb1[r] = cb0[r] - slope2 * 32.0f;
  }

  bf16x8 qf[4];
#pragma unroll
  for (int tt = 0; tt < 4; ++tt)
    qf[tt] = *reinterpret_cast<const bf16x8*>(Qh + (size_t)q_glob * 64 + tt * 16 + hi * 8);

  // issue prologue staging for this split's first tile (async; may be unused)
  stage_tile64(Kh + (size_t)(t0 * 64) * 64, 64, 0, Kb[0], lane, wv);
  stage_tile64(VTh, 2048, t0 * 64, Vb[0], lane, wv);

  // --- integrated prepass: qq, tile-0 QK^T (direct global), m_floor, blt ---
  float qq = 0.0f;
#pragma unroll
  for (int tt = 0; tt < 4; ++tt)
#pragma unroll
    for (int e = 0; e < 8; ++e) {
      const float x = (float)qf[tt][e];
      qq = __builtin_fmaf(x, x, qq);
    }
  qq += __shfl_xor(qq, 32);
#pragma unroll
  for (int off = 1; off <= 16; off <<= 1) qq = fmaxf(qq, __shfl_xor(qq, off));
  {
    f32x16 s0 = {}, s1 = {};
#pragma unroll
    for (int tt = 0; tt < 4; ++tt) {
      bf16x8 k0 = *reinterpret_cast<const bf16x8*>(Kh + (size_t)lq * 64 + tt * 16 + hi * 8);
      s0 = __builtin_amdgcn_mfma_f32_32x32x16_bf16(k0, qf[tt], s0, 0, 0, 0);
      bf16x8 k1 =
          *reinterpret_cast<const bf16x8*>(Kh + (size_t)(32 + lq) * 64 + tt * 16 + hi * 8);
      s1 = __builtin_amdgcn_mfma_f32_32x32x16_bf16(k1, qf[tt], s1, 0, 0, 0);
    }
    float zmax = -3.0e38f;
#pragma unroll
    for (int r = 0; r < 16; ++r) {
      const float x0 = __builtin_fmaf(s0[r], SC2, cb0[r]);
      const float x1 = __builtin_fmaf(s1[r], SC2, cb1[r]);
      zmax = fmaxf(zmax, fmaxf(x0, x1));
    }
    zmax = fmaxf(zmax, __shfl_xor(zmax, 32));  // row max (j-only domain)
    float zmin = zmax;
#pragma unroll
    for (int off = 1; off <= 16; off <<= 1) zmin = fminf(zmin, __shfl_xor(zmin, off));
    if (lane == 0) {
      sred[wv] = zmin;
      sred[2 + wv] = qq;
    }
  }
  __syncthreads();  // sred ready; prologue staging drained
  const float m_floor = fminf(sred[0], sred[1]);
  const float qn = sqrtf(fmaxf(sred[2], sred[3]));
  const float blt = qn * sqrtf(__uint_as_float(nb2[bh])) * SC2;
  // active global tiles [0, T_act): tile t live iff blt - slope2*64*t >= m_floor - 34
  const float tf = (blt - m_floor + 34.0f) / (slope2 * 64.0f);
  const int T_act = min(32, (int)tf + 1);
  const int nt = min(Ct, T_act - t0);
  if (nt <= 0) {  // inactive split: sentinel only
    mlb[threadIdx.x] = threadIdx.x < 64 ? -3.0e38f : 0.0f;
    return;
  }
  float* ob = Opart + ((size_t)idx * nsplit + sp) * 4096;

  f32x16 acc0 = {}, acc1 = {};
  float m_run = m_floor, l_run = 0.0f;

  for (int ti = 0; ti < nt; ++ti) {
    const int kv0 = (t0 + ti) * 64;
    const float s2k = slope2 * (float)kv0;
    const unsigned short* Kc = Kb[ti & 1];
    const unsigned short* Vc = Vb[ti & 1];
    if (ti + 1 < nt) {
      stage_tile64(Kh + (size_t)(kv0 + 64) * 64, 64, 0, Kb[(ti + 1) & 1], lane, wv);
      stage_tile64(VTh, 2048, kv0 + 64, Vb[(ti + 1) & 1], lane, wv);
    }
    f32x16 s0 = {}, s1 = {};
    __builtin_amdgcn_s_setprio(1);
#pragma unroll
    for (int tt = 0; tt < 4; ++tt) {
      {
        const int row = lq;
        const int ch = (tt * 2 + hi) ^ (row & 7);
        bf16x8 kf = *reinterpret_cast<const bf16x8*>(Kc + row * 64 + ch * 8);
        s0 = __builtin_amdgcn_mfma_f32_32x32x16_bf16(kf, qf[tt], s0, 0, 0, 0);
      }
      {
        const int row = 32 + lq;
        const int ch = (tt * 2 + hi) ^ (row & 7);
        bf16x8 kf = *reinterpret_cast<const bf16x8*>(Kc + row * 64 + ch * 8);
        s1 = __builtin_amdgcn_mfma_f32_32x32x16_bf16(kf, qf[tt], s1, 0, 0, 0);
      }
    }
    __builtin_amdgcn_s_setprio(0);
    float zmax = -3.0e38f;
#pragma unroll
    for (int r = 0; r < 16; ++r) {
      s0[r] = __builtin_fmaf(s0[r], SC2, cb0[r]);
      s1[r] = __builtin_fmaf(s1[r], SC2, cb1[r]);
      zmax = fmaxf(zmax, fmaxf(s0[r], s1[r]));
    }
    zmax = fmaxf(zmax, __shfl_xor(zmax, 32));
    const float tmax_true = zmax - s2k;
    if (__any(tmax_true > m_run + 8.0f)) {  // defer-max
      const float m_new = fmaxf(m_run, tmax_true);
      const float alpha = fexp2(m_run - m_new);
      m_run = m_new;
      l_run *= alpha;
      acc0 *= alpha;
      acc1 *= alpha;
    }
    const float mm = m_run + s2k;
    float ps0 = 0.0f, ps1 = 0.0f;
#pragma unroll
    for (int r = 0; r < 16; ++r) {
      const float p0 = fexp2(s0[r] - mm);
      const float p1 = fexp2(s1[r] - mm);
      s0[r] = p0;
      s1[r] = p1;
      ps0 += p0;
      ps1 += p1;
    }
    float psum = ps0 + ps1;
    psum += __shfl_xor(psum, 32);
    l_run += psum;
    bf16x8 pf[4];
#pragma unroll
    for (int half = 0; half < 2; ++half) {
      u32 w0 = cvtpk(s0[half * 8 + 0], s0[half * 8 + 1]);
      u32 w2 = cvtpk(s0[half * 8 + 4], s0[half * 8 + 5]);
      plswap(w0, w2);
      u32 w1 = cvtpk(s0[half * 8 + 2], s0[half * 8 + 3]);
      u32 w3 = cvtpk(s0[half * 8 + 6], s0[half * 8 + 7]);
      plswap(w1, w3);
      u32x4v ww = {w0, w1, w2, w3};
      pf[half] = __builtin_bit_cast(bf16x8, ww);
    }
#pragma unroll
    for (int half = 0; half < 2; ++half) {
      u32 w0 = cvtpk(s1[half * 8 + 0], s1[half * 8 + 1]);
      u32 w2 = cvtpk(s1[half * 8 + 4], s1[half * 8 + 5]);
      plswap(w0, w2);
      u32 w1 = cvtpk(s1[half * 8 + 2], s1[half * 8 + 3]);
      u32 w3 = cvtpk(s1[half * 8 + 6], s1[half * 8 + 7]);
      plswap(w1, w3);
      u32x4v ww = {w0, w1, w2, w3};
      pf[2 + half] = __builtin_bit_cast(bf16x8, ww);
    }
    __builtin_amdgcn_s_setprio(1);
#pragma unroll
    for (int tt = 0; tt < 4; ++tt) {
      {
        const int row = lq;
        const int ch = (tt * 2 + hi) ^ (row & 7);
        bf16x8 vf = *reinterpret_cast<const bf16x8*>(Vc + row * 64 + ch * 8);
        acc0 = __builtin_amdgcn_mfma_f32_32x32x16_bf16(vf, pf[tt], acc0, 0, 0, 0);
      }
      {
        const int row = 32 + lq;
        const int ch = (tt * 2 + hi) ^ (row & 7);
        bf16x8 vf = *reinterpret_cast<const bf16x8*>(Vc + row * 64 + ch * 8);
        acc1 = __builtin_amdgcn_mfma_f32_32x32x16_bf16(vf, pf[tt], acc1, 0, 0, 0);
      }
    }
    __builtin_amdgcn_s_setprio(0);
    __syncthreads();
  }
  const int qloc = wv * 32 + lq;
  if (hi == 0) {
    mlb[qloc] = m_run;
    mlb[64 + qloc] = l_run;
  }
#pragma unroll
  for (int g = 0; g < 4; ++g) {
    f32x4 w0, w1;
#pragma unroll
    for (int e = 0; e < 4; ++e) {
      w0[e] = acc0[g * 4 + e];
      w1[e] = acc1[g * 4 + e];
    }
    *reinterpret_cast<f32x4*>(ob + qloc * 64 + g * 8 + 4 * hi) = w0;
    *reinterpret_cast<f32x4*>(ob + qloc * 64 + 32 + g * 8 + 4 * hi) = w1;
  }
}

// ---------- combine partials -> Obf bf16 [B,S,H*64] ----------

__global__ __launch_bounds__(256) void attn_combine(const float* __restrict__ ML,
                                                    const float* __restrict__ Opart,
                                                    unsigned short* __restrict__ Ob, int nsplit) {
  const int idx = blockIdx.x;  // bh*32 + qt
  const int bh = idx >> 5, qt = idx & 31;
  const int h = bh & 15, b = bh >> 4;
  const int q = threadIdx.x >> 2, d0 = (threadIdx.x & 3) * 16;
  const float* mlb = ML + (size_t)idx * nsplit * 128;
  const float* ob = Opart + (size_t)idx * nsplit * 4096;
  float m_g = -3.0e38f;
  for (int s = 0; s < nsplit; ++s) m_g = fmaxf(m_g, mlb[s * 128 + q]);
  float l = 0.0f;
  f32x4 acc[4] = {};
  for (int s = 0; s < nsplit; ++s) {
    const float ms = mlb[s * 128 + q], ls = mlb[s * 128 + 64 + q];
    const float w = fexp2(ms - m_g);
    const float wl = w * ls;
    if (wl > 0.0f) {
      l += wl;
      const f32x4* src = reinterpret_cast<const f32x4*>(ob + (size_t)s * 4096 + q * 64 + d0);
#pragma unroll
      for (int j = 0; j < 4; ++j) {
        f32x4 v = src[j];
#pragma unroll
        for (int e = 0; e < 4; ++e) acc[j][e] = __builtin_fmaf(w, v[e], acc[j][e]);
      }
    }
  }
  const float invl = 1.0f / l;
  unsigned short* orow = Ob + ((size_t)(b * 2048 + qt * 64 + q)) * 1024 + h * 64 + d0;
#pragma unroll
  for (int j = 0; j < 4; ++j) {
    u16x4 pk;
#pragma unroll
    for (int e = 0; e < 4; ++e) pk[e] = f2bf(acc[j][e] * invl);
    *reinterpret_cast<u16x4*>(orow + j * 4) = pk;
  }
}

// ---------- launcher ----------

extern "C" void kernel_launch(void* const* d_in, const int* in_sizes, int n_in, void* d_out,
                              int out_size, void* d_ws, size_t ws_size, hipStream_t stream) {
  const float* q = (const float*)d_in[0];
  const float* k = (const float*)d_in[1];
  const float* v = (const float*)d_in[2];
  const float* Wq = (const float*)d_in[3];
  const float* bq = (const float*)d_in[4];
  const float* Wk = (const float*)d_in[5];
  const float* bk = (const float*)d_in[6];
  const float* Wv = (const float*)d_in[7];
  const float* bv = (const float*)d_in[8];
  const float* Wo = (const float*)d_in[9];
  const float* bo = (const float*)d_in[10];

  char* ws = (char*)d_ws;
  const size_t MB = 1024 * 1024;
  unsigned short* qb = (unsigned short*)(ws + 0 * MB);    // dead after gemm_qkv
  unsigned short* kb = (unsigned short*)(ws + 8 * MB);    // dead after gemm_qkv
  unsigned short* vb = (unsigned short*)(ws + 16 * MB);   // dead after gemm_qkv
  unsigned short* Wqb = (unsigned short*)(ws + 24 * MB);  // dead after gemm_qkv
  unsigned short* Wkb = (unsigned short*)(ws + 26 * MB);  // dead after gemm_qkv
  unsigned short* Wvb = (unsigned short*)(ws + 28 * MB);  // dead after gemm_qkv
  unsigned short* Wob = (unsigned short*)(ws + 30 * MB);  // LIVE until gemm_out
  unsigned short* Qp = (unsigned short*)(ws + 32 * MB);
  unsigned short* Kp = (unsigned short*)(ws + 40 * MB);
  unsigned short* VTp = (unsigned short*)(ws + 48 * MB);
  unsigned short* Obf = (unsigned short*)(ws + 0 * MB);  // reuse qb

  int nsplit;
  float *ML, *Opart;
  unsigned* nb2;
  bool fold_knorm;
  if (ws_size >= (size_t)121 * MB) nsplit = 4;
  else if (ws_size >= (size_t)89 * MB) nsplit = 2;
  else nsplit = 1;
  if (ws_size >= (size_t)73 * MB) {
    fold_knorm = true;
    nb2 = (unsigned*)(ws + 56 * MB);      // beyond all gemm I/O: safe for in-gemm atomics
    ML = (float*)(ws + 26 * MB + 65536);  // Wkb dead post-gemm
    Opart = (float*)(ws + 56 * MB + 4096);
  } else {
    fold_knorm = false;
    nsplit = 1;
    nb2 = (unsigned*)(ws + 26 * MB);  // Wkb region, written only AFTER gemm (knorm kernel)
    ML = (float*)(ws + 26 * MB + 65536);
    Opart = (float*)(ws + 8 * MB);
  }
  const int Ct = 32 / nsplit;

  // primary path: nb2 zeroed inside cvt_all (nb2 disjoint from cvt destinations);
  // compact path: nb2 aliases Wkb (a cvt destination) -> explicit memset AFTER gemm
  // is impossible (knorm follows immediately), so memset before knorm instead.
  cvt_all<<<8192, 256, 0, stream>>>(q, k, v, Wq, Wk, Wv, Wo, qb, kb, vb, Wqb, Wkb, Wvb, Wob,
                                    fold_knorm ? nb2 : nullptr);
  gemm_qkv_kernel<<<dim3(32, 8, 3), 256, 0, stream>>>(qb, kb, vb, Wqb, Wkb, Wvb, bq, bk, bv, Qp,
                                                      Kp, VTp, fold_knorm ? nb2 : nullptr);
  if (!fold_knorm) {
    hipMemsetAsync(nb2, 0, 64 * sizeof(unsigned), stream);
    knorm_kernel<<<dim3(8, 32), 256, 0, stream>>>(Kp, nb2);
  }
  attn_split_kernel<<<dim3(32, nsplit, 32), 128, 0, stream>>>(Qp, Kp, VTp, nb2, ML, Opart, Ct,
                                                              nsplit);
  attn_combine<<<1024, 256, 0, stream>>>(ML, Opart, Obf, nsplit);
  gemm_out_kernel<<<dim3(32, 8), 256, 0, stream>>>(Obf, Wob, bo, (float*)d_out);
}